// Round 2
// baseline (434.101 us; speedup 1.0000x reference)
//
#include <hip/hip_runtime.h>
#include <hip/hip_bf16.h>
#include <stdint.h>

typedef __attribute__((ext_vector_type(8))) short bf16x8;
typedef __attribute__((ext_vector_type(4))) float f32x4;

__device__ __forceinline__ unsigned f2bf(float f){
  unsigned u = __builtin_bit_cast(unsigned, f);
  return (u + 0x7FFFu + ((u >> 16) & 1u)) >> 16;   // RNE
}
__device__ __forceinline__ float bf2f(unsigned s){
  unsigned u = s << 16; return __builtin_bit_cast(float, u);
}

// ---------- x (fp32) -> bf16 ----------
__global__ void k_cvt_x(const float* __restrict__ x, uint2* __restrict__ xb, int n4){
  int t = blockIdx.x * 256 + threadIdx.x;
  if (t >= n4) return;
  float4 v = reinterpret_cast<const float4*>(x)[t];
  uint2 o;
  o.x = f2bf(v.x) | (f2bf(v.y) << 16);
  o.y = f2bf(v.z) | (f2bf(v.w) << 16);
  xb[t] = o;
}

// ---------- stacked transposed bf16 weights ----------
// Wt1[o][r*128+k] = W1[r][k][o] (r<8); Wt1[o][1024+k] = root1[k][o]   (o<128)
// Wt2 same with W2/root2 (o<64)
__global__ void k_cvt_w(const float* __restrict__ W1, const float* __restrict__ r1,
                        const float* __restrict__ W2, const float* __restrict__ r2,
                        short* __restrict__ Wt1, short* __restrict__ Wt2){
  int t = blockIdx.x * 256 + threadIdx.x;
  if (t < 128 * 1152){
    int o = t / 1152, ka = t - o * 1152, r = ka >> 7, k = ka & 127;
    float v = (r < 8) ? W1[(r * 128 + k) * 128 + o] : r1[k * 128 + o];
    Wt1[t] = (short)f2bf(v);
  } else if (t < 128 * 1152 + 64 * 1152){
    int t2 = t - 128 * 1152;
    int o = t2 / 1152, ka = t2 - o * 1152, r = ka >> 7, k = ka & 127;
    float v = (r < 8) ? W2[(r * 128 + k) * 64 + o] : r2[k * 64 + o];
    Wt2[t2] = (short)f2bf(v);
  }
}

// ---------- per-(rel,dst) degree ----------
__global__ void k_count(const int* __restrict__ ei, const int* __restrict__ et,
                        int* __restrict__ degr, int E, int N){
  int e = blockIdx.x * 256 + threadIdx.x;
  if (e >= E) return;
  unsigned dst = (unsigned)ei[E + e];
  int rel = et[e] & 7;
  if (dst < (unsigned)N) atomicAdd(&degr[rel * N + dst], 1);
}

// ---------- hierarchical exclusive scan over M entries ----------
__global__ void k_scan1(const int* __restrict__ cnt, int* __restrict__ incl,
                        int* __restrict__ bsum, int M){
  __shared__ int s[256];
  int i = blockIdx.x * 256 + threadIdx.x;
  int v = (i < M) ? cnt[i] : 0;
  s[threadIdx.x] = v; __syncthreads();
  for (int d = 1; d < 256; d <<= 1){
    int t = (threadIdx.x >= d) ? s[threadIdx.x - d] : 0;
    __syncthreads();
    s[threadIdx.x] += t;
    __syncthreads();
  }
  if (i < M) incl[i] = s[threadIdx.x];
  if (threadIdx.x == 255) bsum[blockIdx.x] = s[255];
}
// single block, chunked inclusive scan of block sums (handles NB up to anything)
__global__ void k_scan2(int* bsum, int NB){
  __shared__ int s[256];
  int t = threadIdx.x;
  int carry = 0;
  for (int c0 = 0; c0 < NB; c0 += 256){
    int i = c0 + t;
    int v = (i < NB) ? bsum[i] : 0;
    s[t] = v; __syncthreads();
    for (int d = 1; d < 256; d <<= 1){
      int u = (t >= d) ? s[t - d] : 0;
      __syncthreads();
      s[t] += u;
      __syncthreads();
    }
    if (i < NB) bsum[i] = s[t] + carry;
    int tot = s[255];
    __syncthreads();
    carry += tot;
  }
}
__global__ void k_fin(const int* __restrict__ cnt, const int* __restrict__ incl,
                      const int* __restrict__ bsum, int* __restrict__ offs, int M){
  int i = blockIdx.x * 256 + threadIdx.x;
  if (i >= M) return;
  int base = (blockIdx.x > 0) ? bsum[blockIdx.x - 1] : 0;
  offs[i] = base + incl[i] - cnt[i];
}

// ---------- scatter edges into per-(rel,dst) CSR; payload = src (ushort) ----------
__global__ void k_fill(const int* __restrict__ ei, const int* __restrict__ et,
                       const int* __restrict__ offs, int* __restrict__ fill,
                       unsigned short* __restrict__ idx, int E, int N){
  int e = blockIdx.x * 256 + threadIdx.x;
  if (e >= E) return;
  unsigned src = (unsigned)ei[e];
  unsigned dst = (unsigned)ei[E + e];
  int rel = et[e] & 7;
  if (dst < (unsigned)N){
    int key = rel * N + (int)dst;
    int p = atomicAdd(&fill[key], 1);
    idx[offs[key] + p] = (unsigned short)src;
  }
}

// ---------- fused aggregate+GEMM ----------
// Block = 64 dst rows, 256 threads (4 waves x 16 rows). 9 K-phases:
// ph<8: aggregate relation-ph rows of feat into LDS A-tile; ph==8: copy own rows.
// Then MFMA vs B-chunk Wt[o][ph*128..]. Epilogue MODE1: bf16(relu*mask); MODE2: fp32.
template<int NF, int MODE>
__global__ __launch_bounds__(256, 3)
void k_fused(const short* __restrict__ feat, const int* __restrict__ degr,
             const int* __restrict__ offs2, const unsigned short* __restrict__ idx2,
             const short* __restrict__ Wt, const float* __restrict__ bias,
             const float* __restrict__ mask, void* __restrict__ outp, int N){
  constexpr int BN = NF * 16;
  __shared__ char sA[64 * 256];
  __shared__ char sB[BN * 256];
  int tid = threadIdx.x, lane = tid & 63, wave = tid >> 6;
  int row0 = blockIdx.x * 64;
  const unsigned* featu = reinterpret_cast<const unsigned*>(feat);
  f32x4 acc[NF];
  f32x4 z = {0.f, 0.f, 0.f, 0.f};
  #pragma unroll
  for (int n = 0; n < NF; n++) acc[n] = z;

  for (int ph = 0; ph < 9; ph++){
    // stage B chunk [BN][128] bf16, XOR-swizzled 16B chunks
    for (int it = tid; it < BN * 16; it += 256){
      int o = it >> 4, c = it & 15;
      *reinterpret_cast<uint4*>(sB + o * 256 + (((c ^ (o & 7))) << 4)) =
        *reinterpret_cast<const uint4*>(Wt + (size_t)o * 1152 + ph * 128 + c * 8);
    }
    if (ph < 8){
      // metadata for this wave's 16 dsts, duplicated across lane&15
      int j16 = lane & 15;
      int dst = row0 + wave * 16 + j16;
      bool vd = dst < N;
      int key = ph * N + (vd ? dst : 0);
      int cntL  = vd ? degr[key] : 0;
      int baseL = vd ? offs2[key] : 0;
      int s0L   = (cntL > 0) ? (int)idx2[baseL] : 0;
      #pragma unroll
      for (int j = 0; j < 16; j++){
        int cj = __builtin_amdgcn_readlane(cntL, j);
        int bj = __builtin_amdgcn_readlane(baseL, j);
        int sj = __builtin_amdgcn_readlane(s0L, j);
        float a0 = 0.f, a1 = 0.f;
        if (cj > 0){
          unsigned u = featu[(size_t)sj * 64 + lane];
          a0 = bf2f(u & 0xFFFFu); a1 = bf2f(u >> 16);
          for (int i = 1; i < cj; i++){
            int s = (int)idx2[bj + i];
            unsigned u2 = featu[(size_t)s * 64 + lane];
            a0 += bf2f(u2 & 0xFFFFu); a1 += bf2f(u2 >> 16);
          }
          float inv = 1.0f / (float)cj;   // mean coef, bucket-uniform
          a0 *= inv; a1 *= inv;
        }
        int row = wave * 16 + j;
        *reinterpret_cast<unsigned*>(sA + row * 256 + ((((lane >> 2) ^ (row & 7))) << 4)
                                     + ((lane & 3) << 2)) = f2bf(a0) | (f2bf(a1) << 16);
      }
    } else {
      // root phase: copy own feature rows
      for (int it = tid; it < 64 * 16; it += 256){
        int r = it >> 4, c = it & 15;
        int grow = row0 + r;
        uint4 vv = {0u, 0u, 0u, 0u};
        if (grow < N) vv = *reinterpret_cast<const uint4*>(feat + (size_t)grow * 128 + c * 8);
        *reinterpret_cast<uint4*>(sA + r * 256 + (((c ^ (r & 7))) << 4)) = vv;
      }
    }
    __syncthreads();
    #pragma unroll
    for (int kk = 0; kk < 4; kk++){
      int arow = wave * 16 + (lane & 15);
      int cha = (kk * 4 + (lane >> 4)) ^ (arow & 7);
      bf16x8 av = *reinterpret_cast<const bf16x8*>(sA + arow * 256 + cha * 16);
      #pragma unroll
      for (int n = 0; n < NF; n++){
        int o = n * 16 + (lane & 15);
        int chb = (kk * 4 + (lane >> 4)) ^ (o & 7);
        bf16x8 bv = *reinterpret_cast<const bf16x8*>(sB + o * 256 + chb * 16);
        acc[n] = __builtin_amdgcn_mfma_f32_16x16x32_bf16(av, bv, acc[n], 0, 0, 0);
      }
    }
    __syncthreads();
  }
  // epilogue: D frag col=lane&15, row=(lane>>4)*4+j
  #pragma unroll
  for (int n = 0; n < NF; n++){
    int col = n * 16 + (lane & 15);
    float bv = bias[col];
    #pragma unroll
    for (int j = 0; j < 4; j++){
      int row = row0 + wave * 16 + ((lane >> 4) << 2) + j;
      if (row < N){
        float v = acc[n][j] + bv;
        if (MODE == 1){
          v = fmaxf(v, 0.f) * mask[(size_t)row * 128 + col];
          reinterpret_cast<short*>(outp)[(size_t)row * 128 + col] = (short)f2bf(v);
        } else {
          reinterpret_cast<float*>(outp)[(size_t)row * BN + col] = v;
        }
      }
    }
  }
}

extern "C" void kernel_launch(void* const* d_in, const int* in_sizes, int n_in,
                              void* d_out, int out_size, void* d_ws, size_t ws_size,
                              hipStream_t stream){
  const float* x    = (const float*)d_in[0];
  const int*   ei   = (const int*)d_in[1];
  const int*   et   = (const int*)d_in[2];
  const float* W1   = (const float*)d_in[3];
  const float* r1   = (const float*)d_in[4];
  const float* b1   = (const float*)d_in[5];
  const float* W2   = (const float*)d_in[6];
  const float* r2   = (const float*)d_in[7];
  const float* b2   = (const float*)d_in[8];
  const float* mask = (const float*)d_in[9];
  int N = in_sizes[0] / 128;
  int E = in_sizes[2];
  int M8 = 8 * N;

  char* ws = (char*)d_ws;
  short*    xb    = (short*)(ws + 0);            // [N][128] bf16
  short*    hb    = (short*)(ws + 12800000);     // [N][128] bf16
  short*    Wt1   = (short*)(ws + 25600000);     // [128][1152]
  short*    Wt2   = (short*)(ws + 25894912);     // [64][1152]
  int*      degr  = (int*)(ws + 26042368);       // [8N]
  int*      fill  = (int*)(ws + 27642368);       // [8N]
  int*      offs2 = (int*)(ws + 29242368);       // [8N]
  int*      incl  = (int*)(ws + 30842368);       // [8N]
  int*      bsum  = (int*)(ws + 32442368);       // [2048]
  unsigned short* idx2 = (unsigned short*)(ws + 32450560); // [E]
  if (ws_size < (size_t)32450560 + (size_t)E * 2) return;

  // zero degr + fill (contiguous)
  hipMemsetAsync(degr, 0, (size_t)M8 * 8, stream);

  int NB = (M8 + 255) / 256;
  k_cvt_w<<<(128*1152 + 64*1152 + 255)/256, 256, 0, stream>>>(W1, r1, W2, r2, Wt1, Wt2);
  k_cvt_x<<<(N*32 + 255)/256, 256, 0, stream>>>(x, (uint2*)xb, N*32);
  k_count<<<(E + 255)/256, 256, 0, stream>>>(ei, et, degr, E, N);
  k_scan1<<<NB, 256, 0, stream>>>(degr, incl, bsum, M8);
  k_scan2<<<1, 256, 0, stream>>>(bsum, NB);
  k_fin<<<NB, 256, 0, stream>>>(degr, incl, bsum, offs2, M8);
  k_fill<<<(E + 255)/256, 256, 0, stream>>>(ei, et, offs2, fill, idx2, E, N);

  int G = (N + 63) / 64;
  k_fused<8, 1><<<G, 256, 0, stream>>>(xb, degr, offs2, idx2, Wt1, b1, mask, hb, N);
  k_fused<4, 2><<<G, 256, 0, stream>>>(hb, degr, offs2, idx2, Wt2, b2, nullptr, d_out, N);
}

// Round 3
// 374.951 us; speedup vs baseline: 1.1578x; 1.1578x over previous
//
#include <hip/hip_runtime.h>
#include <hip/hip_bf16.h>
#include <stdint.h>

typedef __attribute__((ext_vector_type(8))) short bf16x8;
typedef __attribute__((ext_vector_type(4))) float f32x4;

__device__ __forceinline__ unsigned f2bf(float f){
  unsigned u = __builtin_bit_cast(unsigned, f);
  return (u + 0x7FFFu + ((u >> 16) & 1u)) >> 16;   // RNE
}
__device__ __forceinline__ float bf2f(unsigned s){
  unsigned u = s << 16; return __builtin_bit_cast(float, u);
}

// ---------- combo: weight cvt + x cvt + per-(rel,dst) degree count ----------
// Wt1[o][r*128+k] = W1[r][k][o] (r<8); Wt1[o][1024+k] = root1[k][o]  (o<128)
// Wt2 likewise (o<64)
__global__ void k_combo(const float* __restrict__ x,
                        const float* __restrict__ W1, const float* __restrict__ r1,
                        const float* __restrict__ W2, const float* __restrict__ r2,
                        const int* __restrict__ ei, const int* __restrict__ et,
                        short* __restrict__ Wt1, short* __restrict__ Wt2,
                        uint2* __restrict__ xb, int* __restrict__ degr,
                        int N, int E, int WB, int XB){
  int b = blockIdx.x, tid = threadIdx.x;
  if (b < WB){
    int t = b * 256 + tid;
    if (t < 128 * 1152){
      int o = t / 1152, ka = t - o * 1152, r = ka >> 7, k = ka & 127;
      float v = (r < 8) ? W1[(r * 128 + k) * 128 + o] : r1[k * 128 + o];
      Wt1[t] = (short)f2bf(v);
    } else if (t < 128 * 1152 + 64 * 1152){
      int t2 = t - 128 * 1152;
      int o = t2 / 1152, ka = t2 - o * 1152, r = ka >> 7, k = ka & 127;
      float v = (r < 8) ? W2[(r * 128 + k) * 64 + o] : r2[k * 64 + o];
      Wt2[t2] = (short)f2bf(v);
    }
  } else if (b < WB + XB){
    int t = (b - WB) * 256 + tid;
    if (t < N * 32){
      float4 v = reinterpret_cast<const float4*>(x)[t];
      uint2 o;
      o.x = f2bf(v.x) | (f2bf(v.y) << 16);
      o.y = f2bf(v.z) | (f2bf(v.w) << 16);
      xb[t] = o;
    }
  } else {
    int e = (b - WB - XB) * 256 + tid;
    if (e < E){
      unsigned dst = (unsigned)ei[E + e];
      int rel = et[e] & 7;
      if (dst < (unsigned)N) atomicAdd(&degr[rel * N + dst], 1);
    }
  }
}

// ---------- hierarchical exclusive scan over M entries ----------
__global__ void k_scan1(const int* __restrict__ cnt, int* __restrict__ incl,
                        int* __restrict__ bsum, int M){
  __shared__ int s[256];
  int i = blockIdx.x * 256 + threadIdx.x;
  int v = (i < M) ? cnt[i] : 0;
  s[threadIdx.x] = v; __syncthreads();
  for (int d = 1; d < 256; d <<= 1){
    int t = (threadIdx.x >= d) ? s[threadIdx.x - d] : 0;
    __syncthreads();
    s[threadIdx.x] += t;
    __syncthreads();
  }
  if (i < M) incl[i] = s[threadIdx.x];
  if (threadIdx.x == 255) bsum[blockIdx.x] = s[255];
}
__global__ void k_scan2(int* bsum, int NB){
  __shared__ int s[256];
  int t = threadIdx.x;
  int carry = 0;
  for (int c0 = 0; c0 < NB; c0 += 256){
    int i = c0 + t;
    int v = (i < NB) ? bsum[i] : 0;
    s[t] = v; __syncthreads();
    for (int d = 1; d < 256; d <<= 1){
      int u = (t >= d) ? s[t - d] : 0;
      __syncthreads();
      s[t] += u;
      __syncthreads();
    }
    if (i < NB) bsum[i] = s[t] + carry;
    int tot = s[255];
    __syncthreads();
    carry += tot;
  }
}
// offs + inverse-degree table (fp32)
__global__ void k_fin(const int* __restrict__ cnt, const int* __restrict__ incl,
                      const int* __restrict__ bsum, int* __restrict__ offs,
                      float* __restrict__ invd, int M){
  int i = blockIdx.x * 256 + threadIdx.x;
  if (i >= M) return;
  int base = (blockIdx.x > 0) ? bsum[blockIdx.x - 1] : 0;
  offs[i] = base + incl[i] - cnt[i];
  int c = cnt[i];
  invd[i] = (c > 0) ? 1.0f / (float)c : 0.0f;
}

// ---------- scatter edges into per-(rel,dst) CSR; payload = src (ushort) ----------
__global__ void k_fill(const int* __restrict__ ei, const int* __restrict__ et,
                       const int* __restrict__ offs, int* __restrict__ fill,
                       unsigned short* __restrict__ idx, int E, int N){
  int e = blockIdx.x * 256 + threadIdx.x;
  if (e >= E) return;
  unsigned src = (unsigned)ei[e];
  unsigned dst = (unsigned)ei[E + e];
  int rel = et[e] & 7;
  if (dst < (unsigned)N){
    int key = rel * N + (int)dst;
    int p = atomicAdd(&fill[key], 1);
    idx[offs[key] + p] = (unsigned short)src;
  }
}

// ---------- fused aggregate+GEMM ----------
// Block = 64 dst rows, 4 waves x 16 rows. 9 K-phases (8 relations + root).
// Aggregation: transposed bucket walk — per round, 16 independent gathers.
template<int NF, int MODE>
__global__ __launch_bounds__(256, 3)
void k_fused(const short* __restrict__ feat, const int* __restrict__ degr,
             const int* __restrict__ offs2, const unsigned short* __restrict__ idx2,
             const float* __restrict__ invd, const short* __restrict__ Wt,
             const float* __restrict__ bias, const float* __restrict__ mask,
             void* __restrict__ outp, int N){
  constexpr int BN = NF * 16;
  __shared__ char sA[64 * 256];
  __shared__ char sB[BN * 256];
  int tid = threadIdx.x, lane = tid & 63, wave = tid >> 6;
  int row0 = blockIdx.x * 64;
  const unsigned* featu = reinterpret_cast<const unsigned*>(feat);
  f32x4 acc[NF];
  f32x4 z = {0.f, 0.f, 0.f, 0.f};
  #pragma unroll
  for (int n = 0; n < NF; n++) acc[n] = z;

  int j16 = lane & 15;
  int dstj = row0 + wave * 16 + j16;
  bool vd = (dstj < N) && (lane < 16);
  int dkey = vd ? dstj : 0;

  // prologue meta for phase 0
  int cnt, base, s0; float inv;
  {
    int key = dkey;
    cnt  = vd ? degr[key] : 0;
    base = vd ? offs2[key] : 0;
    inv  = vd ? invd[key] : 0.f;
    s0   = (cnt > 0) ? (int)idx2[base] : -1;
  }

  for (int ph = 0; ph < 9; ph++){
    // ---- stage B chunk [BN][128] bf16, XOR-swizzled 16B chunks ----
    for (int it = tid; it < BN * 16; it += 256){
      int o = it >> 4, c = it & 15;
      *reinterpret_cast<uint4*>(sB + o * 256 + ((c ^ (o & 7)) << 4)) =
        *reinterpret_cast<const uint4*>(Wt + (size_t)o * 1152 + ph * 128 + c * 8);
    }
    if (ph < 8){
      float a0[16], a1[16];
      #pragma unroll
      for (int j = 0; j < 16; j++){ a0[j] = 0.f; a1[j] = 0.f; }

      // wave-local max bucket size (lanes 0-15 hold counts)
      int mx = cnt;
      #pragma unroll
      for (int d = 1; d < 16; d <<= 1) mx = max(mx, __shfl_xor(mx, d));
      int kmax = __builtin_amdgcn_readfirstlane(mx);

      // round 0 uses prefetched s0; rounds k>=1 load idx2[base+k]
      for (int k = 0; k < kmax; k++){
        int sk = (k == 0) ? s0 : ((cnt > k) ? (int)idx2[base + k] : -1);
        unsigned g[16];
        int sj[16];
        #pragma unroll
        for (int j = 0; j < 16; j++){
          sj[j] = __builtin_amdgcn_readlane(sk, j);
          int sc = (sj[j] >= 0) ? sj[j] : 0;          // clamp: row 0, L1-hot
          g[j] = featu[(size_t)(unsigned)sc * 64 + lane];
        }
        #pragma unroll
        for (int j = 0; j < 16; j++){
          float w = (sj[j] >= 0) ? 1.0f : 0.0f;        // scalar weight
          a0[j] = fmaf(w, bf2f(g[j] & 0xFFFFu), a0[j]);
          a1[j] = fmaf(w, bf2f(g[j] >> 16), a1[j]);
        }
      }
      // scale by 1/deg and write LDS (swizzled)
      int invbits = __builtin_bit_cast(int, inv);
      #pragma unroll
      for (int j = 0; j < 16; j++){
        float invj = __builtin_bit_cast(float, __builtin_amdgcn_readlane(invbits, j));
        int row = wave * 16 + j;
        unsigned val = f2bf(a0[j] * invj) | (f2bf(a1[j] * invj) << 16);
        *reinterpret_cast<unsigned*>(sA + row * 256 + (((lane >> 2) ^ (row & 7)) << 4)
                                     + ((lane & 3) << 2)) = val;
      }
    } else {
      // root phase: copy own feature rows
      for (int it = tid; it < 64 * 16; it += 256){
        int r = it >> 4, c = it & 15;
        int grow = row0 + r;
        uint4 vv = {0u, 0u, 0u, 0u};
        if (grow < N) vv = *reinterpret_cast<const uint4*>(feat + (size_t)grow * 128 + c * 8);
        *reinterpret_cast<uint4*>(sA + r * 256 + ((c ^ (r & 7)) << 4)) = vv;
      }
    }
    // prefetch next-phase metadata (hidden under barrier + MFMA)
    if (ph < 7){
      int key = (ph + 1) * N + dkey;
      int cntN  = vd ? degr[key] : 0;
      int baseN = vd ? offs2[key] : 0;
      float invN = vd ? invd[key] : 0.f;
      int s0N = (cntN > 0) ? (int)idx2[baseN] : -1;
      __syncthreads();
      // MFMA
      #pragma unroll
      for (int kk = 0; kk < 4; kk++){
        int arow = wave * 16 + (lane & 15);
        int cha = (kk * 4 + (lane >> 4)) ^ (arow & 7);
        bf16x8 av = *reinterpret_cast<const bf16x8*>(sA + arow * 256 + cha * 16);
        #pragma unroll
        for (int n = 0; n < NF; n++){
          int o = n * 16 + (lane & 15);
          int chb = (kk * 4 + (lane >> 4)) ^ (o & 7);
          bf16x8 bv = *reinterpret_cast<const bf16x8*>(sB + o * 256 + chb * 16);
          acc[n] = __builtin_amdgcn_mfma_f32_16x16x32_bf16(av, bv, acc[n], 0, 0, 0);
        }
      }
      __syncthreads();
      cnt = cntN; base = baseN; inv = invN; s0 = s0N;
    } else {
      __syncthreads();
      #pragma unroll
      for (int kk = 0; kk < 4; kk++){
        int arow = wave * 16 + (lane & 15);
        int cha = (kk * 4 + (lane >> 4)) ^ (arow & 7);
        bf16x8 av = *reinterpret_cast<const bf16x8*>(sA + arow * 256 + cha * 16);
        #pragma unroll
        for (int n = 0; n < NF; n++){
          int o = n * 16 + (lane & 15);
          int chb = (kk * 4 + (lane >> 4)) ^ (o & 7);
          bf16x8 bv = *reinterpret_cast<const bf16x8*>(sB + o * 256 + chb * 16);
          acc[n] = __builtin_amdgcn_mfma_f32_16x16x32_bf16(av, bv, acc[n], 0, 0, 0);
        }
      }
      __syncthreads();
    }
  }
  // epilogue: D frag col=lane&15, row=(lane>>4)*4+j
  #pragma unroll
  for (int n = 0; n < NF; n++){
    int col = n * 16 + (lane & 15);
    float bv = bias[col];
    #pragma unroll
    for (int j = 0; j < 4; j++){
      int row = row0 + wave * 16 + ((lane >> 4) << 2) + j;
      if (row < N){
        float v = acc[n][j] + bv;
        if (MODE == 1){
          v = fmaxf(v, 0.f) * mask[(size_t)row * 128 + col];
          reinterpret_cast<short*>(outp)[(size_t)row * 128 + col] = (short)f2bf(v);
        } else {
          reinterpret_cast<float*>(outp)[(size_t)row * BN + col] = v;
        }
      }
    }
  }
}

extern "C" void kernel_launch(void* const* d_in, const int* in_sizes, int n_in,
                              void* d_out, int out_size, void* d_ws, size_t ws_size,
                              hipStream_t stream){
  const float* x    = (const float*)d_in[0];
  const int*   ei   = (const int*)d_in[1];
  const int*   et   = (const int*)d_in[2];
  const float* W1   = (const float*)d_in[3];
  const float* r1   = (const float*)d_in[4];
  const float* b1   = (const float*)d_in[5];
  const float* W2   = (const float*)d_in[6];
  const float* r2   = (const float*)d_in[7];
  const float* b2   = (const float*)d_in[8];
  const float* mask = (const float*)d_in[9];
  int N = in_sizes[0] / 128;
  int E = in_sizes[2];
  int M8 = 8 * N;

  char* ws = (char*)d_ws;
  short*    xb    = (short*)(ws + 0);            // [N][128] bf16
  short*    hb    = (short*)(ws + 12800000);     // [N][128] bf16
  short*    Wt1   = (short*)(ws + 25600000);     // [128][1152]
  short*    Wt2   = (short*)(ws + 25894912);     // [64][1152]
  int*      degr  = (int*)(ws + 26042368);       // [8N]
  int*      fill  = (int*)(ws + 27642368);       // [8N]
  int*      offs2 = (int*)(ws + 29242368);       // [8N]
  int*      incl  = (int*)(ws + 30842368);       // [8N]
  float*    invd  = (float*)(ws + 32442368);     // [8N]
  int*      bsum  = (int*)(ws + 34042368);       // [2048]
  unsigned short* idx2 = (unsigned short*)(ws + 34050560); // [E]
  if (ws_size < (size_t)34050560 + (size_t)E * 2) return;

  // zero degr + fill (contiguous)
  hipMemsetAsync(degr, 0, (size_t)M8 * 8, stream);

  int WB = (128*1152 + 64*1152 + 255) / 256;
  int XB = (N * 32 + 255) / 256;
  int EB = (E + 255) / 256;
  int NB = (M8 + 255) / 256;
  k_combo<<<WB + XB + EB, 256, 0, stream>>>(x, W1, r1, W2, r2, ei, et,
                                            Wt1, Wt2, (uint2*)xb, degr, N, E, WB, XB);
  k_scan1<<<NB, 256, 0, stream>>>(degr, incl, bsum, M8);
  k_scan2<<<1, 256, 0, stream>>>(bsum, NB);
  k_fin<<<NB, 256, 0, stream>>>(degr, incl, bsum, offs2, invd, M8);
  k_fill<<<EB, 256, 0, stream>>>(ei, et, offs2, fill, idx2, E, N);

  int G = (N + 63) / 64;
  k_fused<8, 1><<<G, 256, 0, stream>>>(xb, degr, offs2, idx2, invd, Wt1, b1, mask, hb, N);
  k_fused<4, 2><<<G, 256, 0, stream>>>(hb, degr, offs2, idx2, invd, Wt2, b2, nullptr, d_out, N);
}